// Round 1
// baseline (42803.198 us; speedup 1.0000x reference)
//
#include <hip/hip_runtime.h>
#include <hip/hip_bf16.h>

#define AGENT __HIP_MEMORY_SCOPE_AGENT

// ---------------- helpers ----------------
__device__ inline float fsig(float x) {
    return 1.0f / (1.0f + __expf(-x));
}
__device__ inline float ftanh(float x) {
    float ax = fabsf(x);
    float e = __expf(-2.0f * ax);
    float r = (1.0f - e) / (1.0f + e);
    return x >= 0.0f ? r : -r;
}
__device__ inline float felu(float x) {
    return x > 0.0f ? x : expm1f(x);
}
__device__ inline float blo(unsigned int u) { return __uint_as_float(u << 16); }
__device__ inline float bhi(unsigned int u) { return __uint_as_float(u & 0xffff0000u); }

// ---------------- conv (stride 2, 3x3, CO=32, NHWC, f32) ----------------
// block = 256 threads: co = tid&31, m = tid>>5 (8 groups), each thread does 2 ox.
template <int CIN>
__global__ void conv_kernel(const float* __restrict__ in, const float* __restrict__ w,
                            const float* __restrict__ bias, float* __restrict__ out,
                            int H, int W, int OH, int OW, int padT, int padL) {
    __shared__ float wsm[9 * CIN * 32];
    const int tid = threadIdx.x;
    for (int i = tid; i < 9 * CIN * 32; i += 256) wsm[i] = w[i];
    __syncthreads();

    const int co = tid & 31;
    const int m = tid >> 5;
    const int t = blockIdx.z;
    const int oy = blockIdx.y;
    const int ox0 = blockIdx.x * 16 + m * 2;

    float acc0 = bias[co];
    float acc1 = acc0;

    for (int ky = 0; ky < 3; ++ky) {
        int iy = 2 * oy + ky - padT;
        if (iy < 0 || iy >= H) continue;
        for (int kx = 0; kx < 3; ++kx) {
            int ix0 = 2 * ox0 + kx - padL;
            int ix1 = ix0 + 2;
            bool v0 = (ox0 < OW) && (ix0 >= 0) && (ix0 < W);
            bool v1 = (ox0 + 1 < OW) && (ix1 >= 0) && (ix1 < W);
            const float* ib0 = in + ((size_t)(t * H + iy) * W + ix0) * CIN;
            const float* ib1 = ib0 + 2 * CIN;
            const float* wrow = &wsm[((ky * 3 + kx) * CIN) * 32 + co];
#pragma unroll
            for (int c4 = 0; c4 < CIN / 4; ++c4) {
                float4 x0 = v0 ? *(const float4*)(ib0 + c4 * 4) : make_float4(0.f, 0.f, 0.f, 0.f);
                float4 x1 = v1 ? *(const float4*)(ib1 + c4 * 4) : make_float4(0.f, 0.f, 0.f, 0.f);
                float w0 = wrow[(c4 * 4 + 0) * 32];
                float w1 = wrow[(c4 * 4 + 1) * 32];
                float w2 = wrow[(c4 * 4 + 2) * 32];
                float w3 = wrow[(c4 * 4 + 3) * 32];
                acc0 += x0.x * w0 + x0.y * w1 + x0.z * w2 + x0.w * w3;
                acc1 += x1.x * w0 + x1.y * w1 + x1.z * w2 + x1.w * w3;
            }
        }
    }
    if (ox0 < OW) out[((size_t)(t * OH + oy) * OW + ox0) * 32 + co] = felu(acc0);
    if (ox0 + 1 < OW) out[((size_t)(t * OH + oy) * OW + ox0 + 1) * 32 + co] = felu(acc1);
}

// ---------------- xpart GEMM: [2048,1152] x [1152,1024] + b -> [2048,1024] ----------------
// BM=64 BN=64 BK=32, block (16,16), 4x4 per thread.
__global__ void gemm_kernel(const float* __restrict__ A, const float* __restrict__ Wx,
                            const float* __restrict__ bias, float* __restrict__ C) {
    __shared__ float As[32][64];  // [k][m]
    __shared__ float Bs[32][64];  // [k][n]
    const int bn = blockIdx.x, bm = blockIdx.y;
    const int tx = threadIdx.x, ty = threadIdx.y;
    const int tid = ty * 16 + tx;

    float acc[4][4] = {};

    for (int k0 = 0; k0 < 1152; k0 += 32) {
        {
            int r = tid >> 3;
            int c = (tid & 7) * 4;
            float4 a0 = *(const float4*)&A[(size_t)(bm * 64 + r) * 1152 + k0 + c];
            float4 a1 = *(const float4*)&A[(size_t)(bm * 64 + r + 32) * 1152 + k0 + c];
            As[c + 0][r] = a0.x; As[c + 1][r] = a0.y; As[c + 2][r] = a0.z; As[c + 3][r] = a0.w;
            As[c + 0][r + 32] = a1.x; As[c + 1][r + 32] = a1.y; As[c + 2][r + 32] = a1.z; As[c + 3][r + 32] = a1.w;
            int rb = tid >> 4;
            int cb = (tid & 15) * 4;
            *(float4*)&Bs[rb][cb] = *(const float4*)&Wx[(size_t)(k0 + rb) * 1024 + bn * 64 + cb];
            *(float4*)&Bs[rb + 16][cb] = *(const float4*)&Wx[(size_t)(k0 + rb + 16) * 1024 + bn * 64 + cb];
        }
        __syncthreads();
#pragma unroll
        for (int kk = 0; kk < 32; ++kk) {
            float4 a = *(float4*)&As[kk][ty * 4];
            float4 b = *(float4*)&Bs[kk][tx * 4];
            acc[0][0] += a.x * b.x; acc[0][1] += a.x * b.y; acc[0][2] += a.x * b.z; acc[0][3] += a.x * b.w;
            acc[1][0] += a.y * b.x; acc[1][1] += a.y * b.y; acc[1][2] += a.y * b.z; acc[1][3] += a.y * b.w;
            acc[2][0] += a.z * b.x; acc[2][1] += a.z * b.y; acc[2][2] += a.z * b.z; acc[2][3] += a.z * b.w;
            acc[3][0] += a.w * b.x; acc[3][1] += a.w * b.y; acc[3][2] += a.w * b.z; acc[3][3] += a.w * b.w;
        }
        __syncthreads();
    }
#pragma unroll
    for (int i = 0; i < 4; ++i) {
        int row = bm * 64 + ty * 4 + i;
#pragma unroll
        for (int j = 0; j < 4; ++j) {
            int col = bn * 64 + tx * 4 + j;
            C[(size_t)row * 1024 + col] = acc[i][j] + bias[col];
        }
    }
}

// ---------------- init ----------------
__global__ void init_kernel(unsigned int* ctr) {
    if (threadIdx.x == 0) ctr[0] = 0u;
}

// ---------------- LSTM recurrence: 4 persistent WGs, bf16 W_h in LDS ----------------
__launch_bounds__(1024)
__global__ void lstm_kernel(const float* __restrict__ lstm_w, const float* __restrict__ xpart,
                            const float* __restrict__ c_in, const float* __restrict__ h_in,
                            float* __restrict__ hs_out, float* hbuf, unsigned int* ctr) {
    __shared__ unsigned short Wb[65536];  // [256 cols][256 k], bf16, XOR-swizzled
    __shared__ float zs[1024];
    __shared__ float zred[256];
    __shared__ float hcur[256];

    const int tid = threadIdx.x;
    const int g = blockIdx.x;      // 0..3, owns hidden units [g*64, g*64+64)
    const int ubase = g * 64;
    const int jj = tid & 255;      // local column: gate q = jj>>6, unit = jj&63
    const int p = tid >> 8;        // k-quarter 0..3
    const int colj = ((jj >> 6) << 8) + ubase + (jj & 63);

    // stage W_h slice (rows 1152..1407 of lstm_w, our 256 columns) as bf16 into LDS
    for (int idx = tid; idx < 65536; idx += 1024) {
        int k = idx >> 8, c = idx & 255;
        int col = ((c >> 6) << 8) + ubase + (c & 63);
        float wv = lstm_w[(size_t)(1152 + k) * 1024 + col];
        __hip_bfloat16 b = __float2bfloat16(wv);
        unsigned short us = *reinterpret_cast<unsigned short*>(&b);
        int byteoff = (((c << 8) + k) << 1) ^ ((c & 7) << 4);
        *reinterpret_cast<unsigned short*>(reinterpret_cast<char*>(Wb) + byteoff) = us;
    }
    float c_state = 0.0f;
    if (tid < 256) hcur[tid] = h_in[tid];
    if (tid < 64) c_state = c_in[ubase + tid];
    __syncthreads();

    const int kbase = p * 64;
    const int swz = (jj & 7) << 4;
    const int rowb = jj << 9;

    for (int t = 0; t < 2048; ++t) {
        float xp = 0.0f;
        if (tid < 256) xp = xpart[(size_t)t * 1024 + colj];

        // partial matvec: acc = sum_{k in [kbase,kbase+64)} hcur[k] * Wh[k][colj]
        float acc = 0.0f;
#pragma unroll
        for (int i = 0; i < 8; ++i) {
            int byteoff = (rowb + ((kbase + i * 8) << 1)) ^ swz;
            uint4 wv = *reinterpret_cast<const uint4*>(reinterpret_cast<const char*>(Wb) + byteoff);
            const float* hp = &hcur[kbase + i * 8];
            float4 h0 = *reinterpret_cast<const float4*>(hp);
            float4 h1 = *reinterpret_cast<const float4*>(hp + 4);
            acc += blo(wv.x) * h0.x + bhi(wv.x) * h0.y;
            acc += blo(wv.y) * h0.z + bhi(wv.y) * h0.w;
            acc += blo(wv.z) * h1.x + bhi(wv.z) * h1.y;
            acc += blo(wv.w) * h1.z + bhi(wv.w) * h1.w;
        }
        zs[p * 256 + jj] = acc;
        __syncthreads();

        if (tid < 256) zred[tid] = zs[tid] + zs[256 + tid] + zs[512 + tid] + zs[768 + tid] + xp;
        __syncthreads();

        if (tid < 64) {
            float zi = zred[tid];
            float zj = zred[64 + tid];
            float zf = zred[128 + tid];
            float zo = zred[192 + tid];
            c_state = c_state * fsig(zf + 1.0f) + fsig(zi) * ftanh(zj);
            float hnew = ftanh(c_state) * fsig(zo);
            hs_out[(size_t)t * 256 + ubase + tid] = hnew;
            __hip_atomic_store(&hbuf[((t + 1) & 1) * 256 + ubase + tid], hnew,
                               __ATOMIC_RELAXED, AGENT);
            __threadfence();
        }
        __syncthreads();

        if (tid == 0) {
            __hip_atomic_fetch_add(ctr, 1u, __ATOMIC_RELEASE, AGENT);
            unsigned int target = 4u * (unsigned int)(t + 1);
            while (__hip_atomic_load(ctr, __ATOMIC_ACQUIRE, AGENT) < target) {
                __builtin_amdgcn_s_sleep(1);
            }
        }
        __syncthreads();

        if (tid < 256)
            hcur[tid] = __hip_atomic_load(&hbuf[((t + 1) & 1) * 256 + tid], __ATOMIC_RELAXED, AGENT);
        __syncthreads();
    }
}

// ---------------- logits: hs[2048,256] @ fc_w[256,18] + fc_b ----------------
__global__ void logits_kernel(const float* __restrict__ hs, const float* __restrict__ fc_w,
                              const float* __restrict__ fc_b, float* __restrict__ out) {
    int idx = blockIdx.x * 256 + threadIdx.x;
    if (idx >= 2048 * 18) return;
    int t = idx / 18, n = idx % 18;
    float acc = fc_b[n];
    const float* hrow = hs + (size_t)t * 256;
#pragma unroll 4
    for (int k = 0; k < 256; ++k) acc += hrow[k] * fc_w[k * 18 + n];
    out[idx] = acc;
}

// ---------------- launch ----------------
extern "C" void kernel_launch(void* const* d_in, const int* in_sizes, int n_in,
                              void* d_out, int out_size, void* d_ws, size_t ws_size,
                              hipStream_t stream) {
    const float* x   = (const float*)d_in[0];
    const float* w0  = (const float*)d_in[1];
    const float* b0  = (const float*)d_in[2];
    const float* w1  = (const float*)d_in[3];
    const float* b1  = (const float*)d_in[4];
    const float* w2  = (const float*)d_in[5];
    const float* b2  = (const float*)d_in[6];
    const float* w3  = (const float*)d_in[7];
    const float* b3  = (const float*)d_in[8];
    const float* lw  = (const float*)d_in[9];
    const float* lb  = (const float*)d_in[10];
    const float* fcw = (const float*)d_in[11];
    const float* fcb = (const float*)d_in[12];
    const float* cin = (const float*)d_in[13];
    const float* hin = (const float*)d_in[14];

    float* outp = (float*)d_out;           // [2048*18] logits, then [2048*256] hs
    float* hs_out = outp + 2048 * 18;

    const size_t N_C0 = (size_t)128 * 42 * 42 * 32;
    const size_t N_C1 = (size_t)128 * 21 * 21 * 32;
    const size_t N_C2 = (size_t)128 * 11 * 11 * 32;
    const size_t N_FE = (size_t)2048 * 1152;
    const size_t N_XP = (size_t)2048 * 1024;

    float* ws    = (float*)d_ws;
    float* c0buf = ws;
    float* c1buf = c0buf + N_C0;
    float* c2buf = c1buf + N_C1;
    float* feats = c2buf + N_C2;
    float* xpart = feats + N_FE;
    float* hbuf  = xpart + N_XP;           // 512 floats (double-buffered h)
    unsigned int* ctr = (unsigned int*)(hbuf + 512);

    // conv stack, T chunked by 128
    for (int ch = 0; ch < 16; ++ch) {
        const float* xin = x + (size_t)ch * 128 * 84 * 84 * 4;
        float* fout = feats + (size_t)ch * 128 * 1152;
        conv_kernel<4><<<dim3(3, 42, 128), 256, 0, stream>>>(xin, w0, b0, c0buf, 84, 84, 42, 42, 0, 0);
        conv_kernel<32><<<dim3(2, 21, 128), 256, 0, stream>>>(c0buf, w1, b1, c1buf, 42, 42, 21, 21, 0, 0);
        conv_kernel<32><<<dim3(1, 11, 128), 256, 0, stream>>>(c1buf, w2, b2, c2buf, 21, 21, 11, 11, 1, 1);
        conv_kernel<32><<<dim3(1, 6, 128), 256, 0, stream>>>(c2buf, w3, b3, fout, 11, 11, 6, 6, 1, 1);
    }

    // xpart = feats @ W_x + b
    gemm_kernel<<<dim3(16, 32), dim3(16, 16), 0, stream>>>(feats, lw, lb, xpart);

    // recurrence
    init_kernel<<<1, 64, 0, stream>>>(ctr);
    lstm_kernel<<<4, 1024, 0, stream>>>(lw, xpart, cin, hin, hs_out, hbuf, ctr);

    // logits
    logits_kernel<<<144, 256, 0, stream>>>(hs_out, fcw, fcb, outp);
}

// Round 3
// 6106.438 us; speedup vs baseline: 7.0095x; 7.0095x over previous
//
#include <hip/hip_runtime.h>
#include <hip/hip_bf16.h>

// ---------------- helpers ----------------
__device__ inline float fsig(float x) { return 1.0f / (1.0f + __expf(-x)); }
__device__ inline float ftanh(float x) {
    float ax = fabsf(x);
    float e = __expf(-2.0f * ax);
    float r = (1.0f - e) / (1.0f + e);
    return x >= 0.0f ? r : -r;
}
__device__ inline float felu(float x) { return x > 0.0f ? x : expm1f(x); }

typedef _Float16 h2_t __attribute__((ext_vector_type(2)));

__device__ inline unsigned int packh2(float a, float b) {
    unsigned short ua = __builtin_bit_cast(unsigned short, (_Float16)a);
    unsigned short ub = __builtin_bit_cast(unsigned short, (_Float16)b);
    return (unsigned int)ua | ((unsigned int)ub << 16);
}

__device__ inline float dot2acc(unsigned int w, unsigned int h, float acc) {
#if __has_builtin(__builtin_amdgcn_fdot2)
    return __builtin_amdgcn_fdot2(__builtin_bit_cast(h2_t, w), __builtin_bit_cast(h2_t, h), acc, false);
#else
    _Float16 wlo = __builtin_bit_cast(_Float16, (unsigned short)(w & 0xffff));
    _Float16 whi = __builtin_bit_cast(_Float16, (unsigned short)(w >> 16));
    _Float16 hlo = __builtin_bit_cast(_Float16, (unsigned short)(h & 0xffff));
    _Float16 hhi = __builtin_bit_cast(_Float16, (unsigned short)(h >> 16));
    return acc + (float)wlo * (float)hlo + (float)whi * (float)hhi;
#endif
}

// ---------------- conv: one block per (t, oy) output row ----------------
template <int CIN, int W, int OW, int PAD>
__global__ __launch_bounds__(256) void conv_row(const float* __restrict__ in,
                                                const float* __restrict__ wg,
                                                const float* __restrict__ bias,
                                                float* __restrict__ out) {
    constexpr int WP = W + 2;
    __shared__ float in_s[3 * WP * CIN];
    constexpr int NQ = 3 * WP * CIN / 4;
    constexpr int QROW = WP * CIN / 4;
    const int tid = threadIdx.x;
    const int oy = blockIdx.x;
    const int t = blockIdx.y;
    const int co = tid & 31;

    for (int q = tid; q < NQ; q += 256) {
        int ky = q / QROW;
        int rem = q - ky * QROW;
        int col = rem / (CIN / 4);
        int c4 = rem - col * (CIN / 4);
        int iy = 2 * oy - PAD + ky;
        int ix = col - 1;
        float4 v = make_float4(0.f, 0.f, 0.f, 0.f);
        if (iy >= 0 && iy < W && ix >= 0 && ix < W)
            v = *(const float4*)&in[(((size_t)t * W + iy) * W + ix) * CIN + c4 * 4];
        *(float4*)&in_s[q * 4] = v;
    }

    if constexpr (CIN == 4) {
        float wr[9][4];
#pragma unroll
        for (int tap = 0; tap < 9; ++tap)
#pragma unroll
            for (int j = 0; j < 4; ++j) wr[tap][j] = wg[(tap * 4 + j) * 32 + co];
        __syncthreads();

        const int g = tid >> 5;
        constexpr int NOX = (OW + 7) / 8;
        float acc[NOX];
#pragma unroll
        for (int m = 0; m < NOX; ++m) acc[m] = 0.f;
#pragma unroll
        for (int ky = 0; ky < 3; ++ky)
#pragma unroll
            for (int kx = 0; kx < 3; ++kx) {
                float w0 = wr[ky * 3 + kx][0], w1 = wr[ky * 3 + kx][1];
                float w2 = wr[ky * 3 + kx][2], w3 = wr[ky * 3 + kx][3];
#pragma unroll
                for (int m = 0; m < NOX; ++m) {
                    int ox = g + 8 * m;
                    if (ox < OW) {
                        int cs = 2 * ox + kx - PAD + 1;
                        float4 xi = *(const float4*)&in_s[(ky * WP + cs) * 4];
                        acc[m] += xi.x * w0 + xi.y * w1 + xi.z * w2 + xi.w * w3;
                    }
                }
            }
        float b = bias[co];
#pragma unroll
        for (int m = 0; m < NOX; ++m) {
            int ox = g + 8 * m;
            if (ox < OW)
                out[(((size_t)t * OW + oy) * OW + ox) * 32 + co] = felu(acc[m] + b);
        }
    } else {
        const int cig = tid >> 5;
        float wr[9][4];
#pragma unroll
        for (int tap = 0; tap < 9; ++tap)
#pragma unroll
            for (int j = 0; j < 4; ++j) wr[tap][j] = wg[(tap * 32 + cig * 4 + j) * 32 + co];
        __syncthreads();

        float acc[OW];
#pragma unroll
        for (int ox = 0; ox < OW; ++ox) acc[ox] = 0.f;
#pragma unroll
        for (int ky = 0; ky < 3; ++ky)
#pragma unroll
            for (int kx = 0; kx < 3; ++kx) {
                const float* ip = &in_s[(ky * WP) * 32 + cig * 4];
                float w0 = wr[ky * 3 + kx][0], w1 = wr[ky * 3 + kx][1];
                float w2 = wr[ky * 3 + kx][2], w3 = wr[ky * 3 + kx][3];
#pragma unroll
                for (int ox = 0; ox < OW; ++ox) {
                    int cs = 2 * ox + kx - PAD + 1;
                    float4 xi = *(const float4*)&ip[cs * 32];
                    acc[ox] += xi.x * w0 + xi.y * w1 + xi.z * w2 + xi.w * w3;
                }
            }
        __shared__ float zs[8][OW * 32];
#pragma unroll
        for (int ox = 0; ox < OW; ++ox) zs[cig][ox * 32 + co] = acc[ox];
        __syncthreads();
        for (int idx = tid; idx < OW * 32; idx += 256) {
            float s = zs[0][idx] + zs[1][idx] + zs[2][idx] + zs[3][idx] +
                      zs[4][idx] + zs[5][idx] + zs[6][idx] + zs[7][idx] + bias[idx & 31];
            out[(((size_t)t * OW + oy) * OW) * 32 + idx] = felu(s);
        }
    }
}

// ---------------- xpart GEMM ----------------
__global__ void gemm_kernel(const float* __restrict__ A, const float* __restrict__ Wx,
                            const float* __restrict__ bias, float* __restrict__ C) {
    __shared__ float As[32][64];
    __shared__ float Bs[32][64];
    const int bn = blockIdx.x, bm = blockIdx.y;
    const int tx = threadIdx.x, ty = threadIdx.y;
    const int tid = ty * 16 + tx;
    float acc[4][4] = {};
    for (int k0 = 0; k0 < 1152; k0 += 32) {
        {
            int r = tid >> 3;
            int c = (tid & 7) * 4;
            float4 a0 = *(const float4*)&A[(size_t)(bm * 64 + r) * 1152 + k0 + c];
            float4 a1 = *(const float4*)&A[(size_t)(bm * 64 + r + 32) * 1152 + k0 + c];
            As[c + 0][r] = a0.x; As[c + 1][r] = a0.y; As[c + 2][r] = a0.z; As[c + 3][r] = a0.w;
            As[c + 0][r + 32] = a1.x; As[c + 1][r + 32] = a1.y; As[c + 2][r + 32] = a1.z; As[c + 3][r + 32] = a1.w;
            int rb = tid >> 4;
            int cb = (tid & 15) * 4;
            *(float4*)&Bs[rb][cb] = *(const float4*)&Wx[(size_t)(k0 + rb) * 1024 + bn * 64 + cb];
            *(float4*)&Bs[rb + 16][cb] = *(const float4*)&Wx[(size_t)(k0 + rb + 16) * 1024 + bn * 64 + cb];
        }
        __syncthreads();
#pragma unroll
        for (int kk = 0; kk < 32; ++kk) {
            float4 a = *(float4*)&As[kk][ty * 4];
            float4 b = *(float4*)&Bs[kk][tx * 4];
            acc[0][0] += a.x * b.x; acc[0][1] += a.x * b.y; acc[0][2] += a.x * b.z; acc[0][3] += a.x * b.w;
            acc[1][0] += a.y * b.x; acc[1][1] += a.y * b.y; acc[1][2] += a.y * b.z; acc[1][3] += a.y * b.w;
            acc[2][0] += a.z * b.x; acc[2][1] += a.z * b.y; acc[2][2] += a.z * b.z; acc[2][3] += a.z * b.w;
            acc[3][0] += a.w * b.x; acc[3][1] += a.w * b.y; acc[3][2] += a.w * b.z; acc[3][3] += a.w * b.w;
        }
        __syncthreads();
    }
#pragma unroll
    for (int i = 0; i < 4; ++i) {
        int row = bm * 64 + ty * 4 + i;
#pragma unroll
        for (int j = 0; j < 4; ++j) {
            int col = bn * 64 + tx * 4 + j;
            C[(size_t)row * 1024 + col] = acc[i][j] + bias[col];
        }
    }
}

// ---------------- LSTM: ONE workgroup on one CU, no global sync ----------------
#define REG_PAIRS 92
#define LDS_PAIRS 36
__global__ __launch_bounds__(1024) void lstm1_kernel(const float* __restrict__ lstm_w,
                                                     const float* __restrict__ xpart,
                                                     const float* __restrict__ c_in,
                                                     const float* __restrict__ h_in,
                                                     float* __restrict__ hs_out) {
    __shared__ unsigned int wl[LDS_PAIRS][1024];
    __shared__ float zs[1024];
    __shared__ uint4 hq4[32];   // 256 f16 h-values = 512 B = 32 uint4 (was 16: LDS overrun bug)
    unsigned short* hsh = (unsigned short*)hq4;

    const int j = threadIdx.x;

    unsigned int wr[REG_PAIRS];
#pragma unroll
    for (int r = 0; r < REG_PAIRS; ++r) {
        float a = lstm_w[(size_t)(1152 + 2 * r) * 1024 + j];
        float b = lstm_w[(size_t)(1152 + 2 * r + 1) * 1024 + j];
        wr[r] = packh2(a, b);
    }
    for (int r = 0; r < LDS_PAIRS; ++r) {
        float a = lstm_w[(size_t)(1152 + 2 * (REG_PAIRS + r)) * 1024 + j];
        float b = lstm_w[(size_t)(1152 + 2 * (REG_PAIRS + r) + 1) * 1024 + j];
        wl[r][j] = packh2(a, b);
    }
    float c_state = 0.0f;
    if (j < 256) {
        c_state = c_in[j];
        hsh[j] = __builtin_bit_cast(unsigned short, (_Float16)h_in[j]);
    }
    __syncthreads();

    float xp = xpart[j];
    for (int t = 0; t < 2048; ++t) {
        float a0 = 0.f, a1 = 0.f, a2 = 0.f, a3 = 0.f;
#pragma unroll
        for (int c = 0; c < 32; ++c) {
            uint4 hq = hq4[c];
            const int r0 = 4 * c;
            unsigned int w0 = (r0 + 0 < REG_PAIRS) ? wr[r0 + 0 < REG_PAIRS ? r0 + 0 : 0] : wl[(r0 + 0 >= REG_PAIRS) ? r0 + 0 - REG_PAIRS : 0][j];
            unsigned int w1 = (r0 + 1 < REG_PAIRS) ? wr[r0 + 1 < REG_PAIRS ? r0 + 1 : 0] : wl[(r0 + 1 >= REG_PAIRS) ? r0 + 1 - REG_PAIRS : 0][j];
            unsigned int w2 = (r0 + 2 < REG_PAIRS) ? wr[r0 + 2 < REG_PAIRS ? r0 + 2 : 0] : wl[(r0 + 2 >= REG_PAIRS) ? r0 + 2 - REG_PAIRS : 0][j];
            unsigned int w3 = (r0 + 3 < REG_PAIRS) ? wr[r0 + 3 < REG_PAIRS ? r0 + 3 : 0] : wl[(r0 + 3 >= REG_PAIRS) ? r0 + 3 - REG_PAIRS : 0][j];
            a0 = dot2acc(w0, hq.x, a0);
            a1 = dot2acc(w1, hq.y, a1);
            a2 = dot2acc(w2, hq.z, a2);
            a3 = dot2acc(w3, hq.w, a3);
        }
        zs[j] = (a0 + a1) + (a2 + a3) + xp;
        float xpn = (t + 1 < 2048) ? xpart[(size_t)(t + 1) * 1024 + j] : 0.f;
        __syncthreads();
        if (j < 256) {
            float zi = zs[j];
            float zg = zs[256 + j];
            float zf = zs[512 + j];
            float zo = zs[768 + j];
            c_state = c_state * fsig(zf + 1.0f) + fsig(zi) * ftanh(zg);
            float h = ftanh(c_state) * fsig(zo);
            hs_out[(size_t)t * 256 + j] = h;
            hsh[j] = __builtin_bit_cast(unsigned short, (_Float16)h);
        }
        __syncthreads();
        xp = xpn;
    }
}

// ---------------- logits ----------------
__global__ void logits_kernel(const float* __restrict__ hs, const float* __restrict__ fc_w,
                              const float* __restrict__ fc_b, float* __restrict__ out) {
    int idx = blockIdx.x * 256 + threadIdx.x;
    if (idx >= 2048 * 18) return;
    int t = idx / 18, n = idx % 18;
    float acc = fc_b[n];
    const float* hrow = hs + (size_t)t * 256;
#pragma unroll 4
    for (int k = 0; k < 256; ++k) acc += hrow[k] * fc_w[k * 18 + n];
    out[idx] = acc;
}

// ---------------- launch ----------------
extern "C" void kernel_launch(void* const* d_in, const int* in_sizes, int n_in,
                              void* d_out, int out_size, void* d_ws, size_t ws_size,
                              hipStream_t stream) {
    const float* x   = (const float*)d_in[0];
    const float* w0  = (const float*)d_in[1];
    const float* b0  = (const float*)d_in[2];
    const float* w1  = (const float*)d_in[3];
    const float* b1  = (const float*)d_in[4];
    const float* w2  = (const float*)d_in[5];
    const float* b2  = (const float*)d_in[6];
    const float* w3  = (const float*)d_in[7];
    const float* b3  = (const float*)d_in[8];
    const float* lw  = (const float*)d_in[9];
    const float* lb  = (const float*)d_in[10];
    const float* fcw = (const float*)d_in[11];
    const float* fcb = (const float*)d_in[12];
    const float* cin = (const float*)d_in[13];
    const float* hin = (const float*)d_in[14];

    float* outp = (float*)d_out;
    float* hs_out = outp + 2048 * 18;

    const size_t PERT = 56448 + 14112 + 3872;
    const size_t FIXED = (size_t)2048 * 1152 + (size_t)2048 * 1024;

    int C = 128;
    const int cands[4] = {2048, 1024, 512, 256};
    for (int i = 0; i < 4; ++i) {
        if ((FIXED + (size_t)cands[i] * PERT) * 4 <= ws_size) { C = cands[i]; break; }
    }

    float* ws    = (float*)d_ws;
    float* c0buf = ws;
    float* c1buf = c0buf + (size_t)C * 56448;
    float* c2buf = c1buf + (size_t)C * 14112;
    float* feats = c2buf + (size_t)C * 3872;
    float* xpart = feats + (size_t)2048 * 1152;

    for (int t0 = 0; t0 < 2048; t0 += C) {
        const float* xin = x + (size_t)t0 * 84 * 84 * 4;
        conv_row<4, 84, 42, 0><<<dim3(42, C), 256, 0, stream>>>(xin, w0, b0, c0buf);
        conv_row<32, 42, 21, 0><<<dim3(21, C), 256, 0, stream>>>(c0buf, w1, b1, c1buf);
        conv_row<32, 21, 11, 1><<<dim3(11, C), 256, 0, stream>>>(c1buf, w2, b2, c2buf);
        conv_row<32, 11, 6, 1><<<dim3(6, C), 256, 0, stream>>>(c2buf, w3, b3,
                                                               feats + (size_t)t0 * 1152);
    }

    gemm_kernel<<<dim3(16, 32), dim3(16, 16), 0, stream>>>(feats, lw, lb, xpart);
    lstm1_kernel<<<1, 1024, 0, stream>>>(lw, xpart, cin, hin, hs_out);
    logits_kernel<<<144, 256, 0, stream>>>(hs_out, fcw, fcb, outp);
}